// Round 6
// baseline (337.246 us; speedup 1.0000x reference)
//
#include <hip/hip_runtime.h>

#define PEPS  1e-5f
#define LOG2E 1.4426950408889634f

__device__ __forceinline__ float fast_rcp(float x) { return __builtin_amdgcn_rcpf(x); }

// out = x * (0.5 + 0.5 * sigmoid((x-m)*rs)), with nrs2 = -rs*log2e, mrs = m*rs*log2e:
// sigmoid((x-m)*rs) = 1/(1+exp2(fma(x,nrs2,mrs)))
__device__ __forceinline__ float patch_one(float x, float nrs2, float mrs) {
    const float e = __builtin_amdgcn_exp2f(fmaf(x, nrs2, mrs));
    return x * fmaf(0.5f, fast_rcp(1.0f + e), 0.5f);
}

__device__ __forceinline__ void wave_reduce2(float& a, float& b) {
#pragma unroll
    for (int off = 32; off; off >>= 1) {
        a += __shfl_xor(a, off);
        b += __shfl_xor(b, off);
    }
}

// One block per 128x128 QUARTER image: 512 thr = 8 waves; wave = 32-row half of
// a 64x64 patch; 32 floats/thread (8 float4 = 32 data VGPRs -> fits the 64-VGPR
// 8-waves/EU budget, no spill; r3-r5 spilled because 64 data VGPRs never could).
// Pass 1 (s=64): wave-pair via LDS. Pass 2 (s=128): block-local (quarter ==
// one 128x128 patch). Pass 3 (s=256): 4-block atomic handshake in ws.
// 4 blocks/CU resident -> one block's load/store overlaps others' compute.
__global__ __launch_bounds__(512)
void fused_pyramid_quarter(const float* __restrict__ in, float* __restrict__ out,
                           float* __restrict__ ws)
{
    constexpr int W = 256;
    const int tid  = threadIdx.x;
    const int wave = tid >> 6;          // 0..7
    const int lane = tid & 63;
    const int img  = blockIdx.x >> 2;
    const int quad = blockIdx.x & 3;    // 2x2 grid of 128x128 quarters
    const int p    = wave >> 1;         // 0..3: 2x2 grid of 64x64 patches in quarter
    const int h    = wave & 1;          // 32-row half of the patch
    const size_t base = (size_t)img * (W * W)
                      + (size_t)((quad >> 1) * 128 + (p >> 1) * 64 + h * 32) * W
                      + (size_t)((quad & 1) * 128 + (p & 1) * 64);

    __shared__ float redS[8], redQ[8], stats[2];

    // ---- load (32 floats/lane) + pass-1 partial sums -----------------------
    float4 v[8];
    float s = 0.f, q = 0.f;
#pragma unroll
    for (int u = 0; u < 8; ++u) {
        const int j  = u * 64 + lane;   // float4 index within 32x64 wave strip
        const int r  = j >> 4;          // 16 float4 per 64-wide row
        const int c4 = j & 15;
        const float4 t = *reinterpret_cast<const float4*>(in + base + (size_t)r * W + c4 * 4);
        v[u] = t;
        s += (t.x + t.y) + (t.z + t.w);
        q = fmaf(t.x, t.x, fmaf(t.y, t.y, fmaf(t.z, t.z, fmaf(t.w, t.w, q))));
    }

    // ---- pass 1 (s=64): patch = this wave + wave^1 -------------------------
    wave_reduce2(s, q);
    if (lane == 0) { redS[wave] = s; redQ[wave] = q; }
    __syncthreads();
    float m  = (redS[wave] + redS[wave ^ 1]) * (1.0f / 4096.0f);
    float rs = rsqrtf(fmaf(-m, m, (redQ[wave] + redQ[wave ^ 1]) * (1.0f / 4096.0f)) + PEPS);
    float nrs2 = rs * -LOG2E;
    float mrs  = m * rs * LOG2E;

    float s2 = 0.f, q2 = 0.f;
#pragma unroll
    for (int u = 0; u < 8; ++u) {
        float4 t = v[u];
        t.x = patch_one(t.x, nrs2, mrs);
        t.y = patch_one(t.y, nrs2, mrs);
        t.z = patch_one(t.z, nrs2, mrs);
        t.w = patch_one(t.w, nrs2, mrs);
        v[u] = t;
        s2 += (t.x + t.y) + (t.z + t.w);
        q2 = fmaf(t.x, t.x, fmaf(t.y, t.y, fmaf(t.z, t.z, fmaf(t.w, t.w, q2))));
    }

    // ---- pass 2 (s=128): block == one 128x128 patch ------------------------
    wave_reduce2(s2, q2);
    __syncthreads();                    // pass-1 partial reads all done
    if (lane == 0) { redS[wave] = s2; redQ[wave] = q2; }
    __syncthreads();
    {
        float S = 0.f, Q = 0.f;
#pragma unroll
        for (int w = 0; w < 8; ++w) { S += redS[w]; Q += redQ[w]; }
        m  = S * (1.0f / 16384.0f);
        rs = rsqrtf(fmaf(-m, m, Q * (1.0f / 16384.0f)) + PEPS);
    }
    nrs2 = rs * -LOG2E;
    mrs  = m * rs * LOG2E;

    float s3 = 0.f, q3 = 0.f;
#pragma unroll
    for (int u = 0; u < 8; ++u) {
        float4 t = v[u];
        t.x = patch_one(t.x, nrs2, mrs);
        t.y = patch_one(t.y, nrs2, mrs);
        t.z = patch_one(t.z, nrs2, mrs);
        t.w = patch_one(t.w, nrs2, mrs);
        v[u] = t;
        s3 += (t.x + t.y) + (t.z + t.w);
        q3 = fmaf(t.x, t.x, fmaf(t.y, t.y, fmaf(t.z, t.z, fmaf(t.w, t.w, q3))));
    }

    // ---- pass 3 (s=256): block partial -> 4-block handshake ----------------
    wave_reduce2(s3, q3);
    __syncthreads();                    // pass-2 partial reads all done
    if (lane == 0) { redS[wave] = s3; redQ[wave] = q3; }
    __syncthreads();
    if (tid == 0) {
        float S = 0.f, Q = 0.f;
#pragma unroll
        for (int w = 0; w < 8; ++w) { S += redS[w]; Q += redQ[w]; }
        float* slot = ws + (size_t)img * 4;        // {S, Q, flag, pad}
        atomicAdd(slot + 0, S);
        atomicAdd(slot + 1, Q);
        __threadfence();                           // partials visible before flag
        unsigned* flag = reinterpret_cast<unsigned*>(slot + 2);
        atomicAdd(flag, 1u);
        while (__hip_atomic_load(flag, __ATOMIC_ACQUIRE, __HIP_MEMORY_SCOPE_AGENT) < 4u)
            __builtin_amdgcn_s_sleep(1);
        const float St = __hip_atomic_load(slot + 0, __ATOMIC_RELAXED, __HIP_MEMORY_SCOPE_AGENT);
        const float Qt = __hip_atomic_load(slot + 1, __ATOMIC_RELAXED, __HIP_MEMORY_SCOPE_AGENT);
        const float mm = St * (1.0f / 65536.0f);
        stats[0] = mm;
        stats[1] = rsqrtf(fmaf(-mm, mm, Qt * (1.0f / 65536.0f)) + PEPS);
    }
    __syncthreads();
    m  = stats[0];
    rs = stats[1];
    nrs2 = rs * -LOG2E;
    mrs  = m * rs * LOG2E;

    // ---- apply pass 3 + store ----------------------------------------------
#pragma unroll
    for (int u = 0; u < 8; ++u) {
        const int j  = u * 64 + lane;
        const int r  = j >> 4;
        const int c4 = j & 15;
        float4 t = v[u];
        t.x = patch_one(t.x, nrs2, mrs);
        t.y = patch_one(t.y, nrs2, mrs);
        t.z = patch_one(t.z, nrs2, mrs);
        t.w = patch_one(t.w, nrs2, mrs);
        *reinterpret_cast<float4*>(out + base + (size_t)r * W + c4 * 4) = t;
    }
}

extern "C" void kernel_launch(void* const* d_in, const int* in_sizes, int n_in,
                              void* d_out, int out_size, void* d_ws, size_t ws_size,
                              hipStream_t stream)
{
    const float* x = (const float*)d_in[0];
    float* out = (float*)d_out;
    constexpr int IMGS = 16 * 64;       // b * c images of 256x256

    // Zero the handshake slots every call (graph-captured; keeps replays
    // deterministic — harness does NOT re-poison d_ws between replays).
    hipMemsetAsync(d_ws, 0, (size_t)IMGS * 4 * sizeof(float), stream);

    fused_pyramid_quarter<<<IMGS * 4, 512, 0, stream>>>(x, out, (float*)d_ws);
}

// Round 7
// 237.891 us; speedup vs baseline: 1.4176x; 1.4176x over previous
//
#include <hip/hip_runtime.h>

#define PEPS  1e-5f
#define LOG2E 1.4426950408889634f

__device__ __forceinline__ float fast_rcp(float x) { return __builtin_amdgcn_rcpf(x); }

// out = x * (0.5 + 0.5 * sigmoid((x-m)*rs)), with nrs2 = -rs*log2e, mrs = m*rs*log2e:
// sigmoid((x-m)*rs) = 1/(1+exp2(fma(x,nrs2,mrs)))
__device__ __forceinline__ float patch_one(float x, float nrs2, float mrs) {
    const float e = __builtin_amdgcn_exp2f(fmaf(x, nrs2, mrs));
    return x * fmaf(0.5f, fast_rcp(1.0f + e), 0.5f);
}

__device__ __forceinline__ void wave_reduce2(float& a, float& b) {
#pragma unroll
    for (int off = 32; off; off >>= 1) {
        a += __shfl_xor(a, off);
        b += __shfl_xor(b, off);
    }
}

// One block per 128x128 QUARTER image: 512 thr = 8 waves; wave = 32-row half of
// a 64x64 patch. The quarter tile lives in LDS (64 KiB), NOT registers:
// r3-r6 showed hipcc spills any multi-float4 per-thread array for 512-thread
// kernels no matter what occupancy attributes say (VGPR_Count 60/64/36, scratch
// SGPR init, ~2x slowdown). With LDS caching, per-thread state is a few scalars
// -> nothing to spill; 64 KiB/block -> 2 blocks/CU -> one block's global
// load/store overlaps the other's compute.
// Pass 1 (s=64): wave-pair stats. Pass 2 (s=128): block-local. Pass 3 (s=256):
// 4-block atomic handshake in ws (structure correctness proven in r3-r6).
__global__ __launch_bounds__(512)
void fused_pyramid_lds(const float* __restrict__ in, float* __restrict__ out,
                       float* __restrict__ ws)
{
    constexpr int W = 256;
    __shared__ float4 tile[4096];       // 64 KiB: [wave][u][lane], wave-private strips
    __shared__ float redS[8], redQ[8], stats[2];

    const int tid  = threadIdx.x;
    const int wave = tid >> 6;          // 0..7
    const int lane = tid & 63;
    const int img  = blockIdx.x >> 2;
    const int quad = blockIdx.x & 3;    // 2x2 grid of 128x128 quarters
    const int p    = wave >> 1;         // 0..3: 2x2 grid of 64x64 patches in quarter
    const int h    = wave & 1;          // 32-row half of the patch
    const size_t base = (size_t)img * (W * W)
                      + (size_t)((quad >> 1) * 128 + (p >> 1) * 64 + h * 32) * W
                      + (size_t)((quad & 1) * 128 + (p & 1) * 64);
    const int tb = wave * 512 + lane;   // this thread's LDS float4 slot for u=0

    // ---- load -> LDS + pass-1 partial sums ---------------------------------
    float s = 0.f, q = 0.f;
#pragma unroll
    for (int u = 0; u < 8; ++u) {
        const int j  = u * 64 + lane;   // float4 index within 32x64 wave strip
        const int r  = j >> 4;          // 16 float4 per 64-wide row
        const int c4 = j & 15;
        const float4 t = *reinterpret_cast<const float4*>(in + base + (size_t)r * W + c4 * 4);
        tile[tb + u * 64] = t;
        s += (t.x + t.y) + (t.z + t.w);
        q = fmaf(t.x, t.x, fmaf(t.y, t.y, fmaf(t.z, t.z, fmaf(t.w, t.w, q))));
    }

    // ---- pass 1 (s=64): patch = this wave + wave^1 -------------------------
    wave_reduce2(s, q);
    if (lane == 0) { redS[wave] = s; redQ[wave] = q; }
    __syncthreads();
    float m  = (redS[wave] + redS[wave ^ 1]) * (1.0f / 4096.0f);
    float rs = rsqrtf(fmaf(-m, m, (redQ[wave] + redQ[wave ^ 1]) * (1.0f / 4096.0f)) + PEPS);
    float nrs2 = rs * -LOG2E;
    float mrs  = m * rs * LOG2E;

    float s2 = 0.f, q2 = 0.f;
#pragma unroll
    for (int u = 0; u < 8; ++u) {
        float4 t = tile[tb + u * 64];
        t.x = patch_one(t.x, nrs2, mrs);
        t.y = patch_one(t.y, nrs2, mrs);
        t.z = patch_one(t.z, nrs2, mrs);
        t.w = patch_one(t.w, nrs2, mrs);
        tile[tb + u * 64] = t;
        s2 += (t.x + t.y) + (t.z + t.w);
        q2 = fmaf(t.x, t.x, fmaf(t.y, t.y, fmaf(t.z, t.z, fmaf(t.w, t.w, q2))));
    }

    // ---- pass 2 (s=128): block == one 128x128 patch ------------------------
    wave_reduce2(s2, q2);
    __syncthreads();                    // pass-1 partial reads all done
    if (lane == 0) { redS[wave] = s2; redQ[wave] = q2; }
    __syncthreads();
    {
        float S = 0.f, Q = 0.f;
#pragma unroll
        for (int w = 0; w < 8; ++w) { S += redS[w]; Q += redQ[w]; }
        m  = S * (1.0f / 16384.0f);
        rs = rsqrtf(fmaf(-m, m, Q * (1.0f / 16384.0f)) + PEPS);
    }
    nrs2 = rs * -LOG2E;
    mrs  = m * rs * LOG2E;

    float s3 = 0.f, q3 = 0.f;
#pragma unroll
    for (int u = 0; u < 8; ++u) {
        float4 t = tile[tb + u * 64];
        t.x = patch_one(t.x, nrs2, mrs);
        t.y = patch_one(t.y, nrs2, mrs);
        t.z = patch_one(t.z, nrs2, mrs);
        t.w = patch_one(t.w, nrs2, mrs);
        tile[tb + u * 64] = t;
        s3 += (t.x + t.y) + (t.z + t.w);
        q3 = fmaf(t.x, t.x, fmaf(t.y, t.y, fmaf(t.z, t.z, fmaf(t.w, t.w, q3))));
    }

    // ---- pass 3 (s=256): block partial -> 4-block handshake ----------------
    wave_reduce2(s3, q3);
    __syncthreads();                    // pass-2 partial reads all done
    if (lane == 0) { redS[wave] = s3; redQ[wave] = q3; }
    __syncthreads();
    if (tid == 0) {
        float S = 0.f, Q = 0.f;
#pragma unroll
        for (int w = 0; w < 8; ++w) { S += redS[w]; Q += redQ[w]; }
        float* slot = ws + (size_t)img * 4;        // {S, Q, flag, pad}
        atomicAdd(slot + 0, S);
        atomicAdd(slot + 1, Q);
        __threadfence();                           // partials visible before flag
        unsigned* flag = reinterpret_cast<unsigned*>(slot + 2);
        atomicAdd(flag, 1u);
        while (__hip_atomic_load(flag, __ATOMIC_ACQUIRE, __HIP_MEMORY_SCOPE_AGENT) < 4u)
            __builtin_amdgcn_s_sleep(1);
        const float St = __hip_atomic_load(slot + 0, __ATOMIC_RELAXED, __HIP_MEMORY_SCOPE_AGENT);
        const float Qt = __hip_atomic_load(slot + 1, __ATOMIC_RELAXED, __HIP_MEMORY_SCOPE_AGENT);
        const float mm = St * (1.0f / 65536.0f);
        stats[0] = mm;
        stats[1] = rsqrtf(fmaf(-mm, mm, Qt * (1.0f / 65536.0f)) + PEPS);
    }
    __syncthreads();
    m  = stats[0];
    rs = stats[1];
    nrs2 = rs * -LOG2E;
    mrs  = m * rs * LOG2E;

    // ---- apply pass 3 + store ----------------------------------------------
#pragma unroll
    for (int u = 0; u < 8; ++u) {
        const int j  = u * 64 + lane;
        const int r  = j >> 4;
        const int c4 = j & 15;
        float4 t = tile[tb + u * 64];
        t.x = patch_one(t.x, nrs2, mrs);
        t.y = patch_one(t.y, nrs2, mrs);
        t.z = patch_one(t.z, nrs2, mrs);
        t.w = patch_one(t.w, nrs2, mrs);
        *reinterpret_cast<float4*>(out + base + (size_t)r * W + c4 * 4) = t;
    }
}

extern "C" void kernel_launch(void* const* d_in, const int* in_sizes, int n_in,
                              void* d_out, int out_size, void* d_ws, size_t ws_size,
                              hipStream_t stream)
{
    const float* x = (const float*)d_in[0];
    float* out = (float*)d_out;
    constexpr int IMGS = 16 * 64;       // b * c images of 256x256

    // Zero the handshake slots every call (graph-captured; keeps replays
    // deterministic — harness does NOT re-poison d_ws between replays).
    hipMemsetAsync(d_ws, 0, (size_t)IMGS * 4 * sizeof(float), stream);

    fused_pyramid_lds<<<IMGS * 4, 512, 0, stream>>>(x, out, (float*)d_ws);
}

// Round 8
// 113.698 us; speedup vs baseline: 2.9662x; 2.0923x over previous
//
#include <hip/hip_runtime.h>

#define PEPS  1e-5f
#define LOG2E 1.4426950408889634f

__device__ __forceinline__ float fast_rcp(float x) { return __builtin_amdgcn_rcpf(x); }

// out = x * (0.5 + 0.5 * sigmoid((x-m)*rs)), with nrs2 = -rs*log2e, mrs = m*rs*log2e
__device__ __forceinline__ float patch_one(float x, float nrs2, float mrs) {
    const float e = __builtin_amdgcn_exp2f(fmaf(x, nrs2, mrs));
    return x * fmaf(0.5f, fast_rcp(1.0f + e), 0.5f);
}

__device__ __forceinline__ void wave_reduce2(float& a, float& b) {
#pragma unroll
    for (int off = 32; off; off >>= 1) {
        a += __shfl_xor(a, off);
        b += __shfl_xor(b, off);
    }
}

// async global->LDS, 16 B per lane. LDS dest is wave-uniform base (+lane*16 by HW),
// global src is per-lane.
__device__ __forceinline__ void gld_lds16(const float* g, float* l) {
    __builtin_amdgcn_global_load_lds(
        (const __attribute__((address_space(1))) void*)g,
        (__attribute__((address_space(3))) void*)l, 16, 0, 0);
}

// Persistent pipeline: grid=256 blocks x 1024 thr, 1 block/CU, each block does
// 4 images. Per image: waves 0-7's data (rows 0..127) comes from an LDS tile
// prefetched asynchronously during the PREVIOUS image's compute+store; waves
// 8-15 load rows 128..255 global->reg directly. No cross-block sync (r3-r7's
// handshake cost ~+100us regardless of spill/LDS). 1024-thr blocks keep the
// allocator at 4 waves/EU (~128 VGPR budget) so v[16] stays in registers (r2
// proved this; 512-thr blocks always spilled).
__global__ __launch_bounds__(1024) void fused_pyramid_pipe(
    const float* __restrict__ in, float* __restrict__ out)
{
    constexpr int W   = 256;
    constexpr int IMG = W * W;                  // 65536 floats
    __shared__ float tile[32768];               // 128 KiB: rows 0..127 of current image
    __shared__ float redS[16], redQ[16];        // pass-2 partials
    __shared__ float redS2[16], redQ2[16];      // pass-3 partials (separate -> fewer barriers)

    const int tid   = threadIdx.x;
    const int wave  = tid >> 6;                 // 0..15 -> 4x4 grid of 64x64 patches
    const int lane  = tid & 63;
    const int pr    = wave >> 2;
    const int pc    = wave & 3;
    const int rlane = lane >> 4;                // row contribution from lane
    const int c4    = lane & 15;
    const int bid   = blockIdx.x;

    // ---- prologue: prefetch image bid's top half into LDS ------------------
    {
        const float* src = in + (size_t)bid * IMG;
#pragma unroll
        for (int i = 0; i < 8; ++i) {
            const int chunk = wave * 8 + i;     // 128 chunks x 1024 B cover 128 KiB
            gld_lds16(src + chunk * 256 + lane * 4, &tile[chunk * 256]);
        }
    }

    for (int k = 0; k < 4; ++k) {
        const int img = bid + k * 256;
        const float* in_img  = in  + (size_t)img * IMG;
        float*       out_img = out + (size_t)img * IMG;

        // A: wait prefetched tile (and prior stores), sync all waves
        asm volatile("s_waitcnt vmcnt(0)" ::: "memory");
        __syncthreads();

        // B: load v[16] + pass-1 sums. Top waves from LDS, bottom from global.
        float4 v[16];
        float s = 0.f, q = 0.f;
        if (wave < 8) {
            const float* tl = &tile[(pr * 64) * W + pc * 64];
#pragma unroll
            for (int u = 0; u < 16; ++u) {
                const int r = u * 4 + rlane;
                const float4 t = *reinterpret_cast<const float4*>(tl + r * W + c4 * 4);
                v[u] = t;
                s += (t.x + t.y) + (t.z + t.w);
                q = fmaf(t.x, t.x, fmaf(t.y, t.y, fmaf(t.z, t.z, fmaf(t.w, t.w, q))));
            }
        } else {
            const float* gl = in_img + (size_t)(pr * 64) * W + pc * 64;
#pragma unroll
            for (int u = 0; u < 16; ++u) {
                const int r = u * 4 + rlane;
                const float4 t = *reinterpret_cast<const float4*>(gl + (size_t)r * W + c4 * 4);
                v[u] = t;
                s += (t.x + t.y) + (t.z + t.w);
                q = fmaf(t.x, t.x, fmaf(t.y, t.y, fmaf(t.z, t.z, fmaf(t.w, t.w, q))));
            }
        }

        // C: pass 1 (s=64), wave-local
        wave_reduce2(s, q);
        float m  = s * (1.0f / 4096.0f);
        float rs = rsqrtf(fmaf(-m, m, q * (1.0f / 4096.0f)) + PEPS);
        float nrs2 = rs * -LOG2E;
        float mrs  = m * rs * LOG2E;

        float s2 = 0.f, q2 = 0.f;
#pragma unroll
        for (int u = 0; u < 16; ++u) {
            float4 t = v[u];
            t.x = patch_one(t.x, nrs2, mrs);
            t.y = patch_one(t.y, nrs2, mrs);
            t.z = patch_one(t.z, nrs2, mrs);
            t.w = patch_one(t.w, nrs2, mrs);
            v[u] = t;
            s2 += (t.x + t.y) + (t.z + t.w);
            q2 = fmaf(t.x, t.x, fmaf(t.y, t.y, fmaf(t.z, t.z, fmaf(t.w, t.w, q2))));
        }

        // D: publish pass-2 partials (also fences all tile reads from B)
        wave_reduce2(s2, q2);
        if (lane == 0) { redS[wave] = s2; redQ[wave] = q2; }
        __syncthreads();

        // E: kick off next image's top-half prefetch (flies under F/G/H)
        if (k < 3) {
            const float* src = in + (size_t)(bid + (k + 1) * 256) * IMG;
#pragma unroll
            for (int i = 0; i < 8; ++i) {
                const int chunk = wave * 8 + i;
                gld_lds16(src + chunk * 256 + lane * 4, &tile[chunk * 256]);
            }
        }

        // F: pass 2 (s=128): 2x2 wave group
        const int w00 = wave & ~5;
        {
            const float S = (redS[w00] + redS[w00 + 1]) + (redS[w00 + 4] + redS[w00 + 5]);
            const float Q = (redQ[w00] + redQ[w00 + 1]) + (redQ[w00 + 4] + redQ[w00 + 5]);
            m  = S * (1.0f / 16384.0f);
            rs = rsqrtf(fmaf(-m, m, Q * (1.0f / 16384.0f)) + PEPS);
        }
        nrs2 = rs * -LOG2E;
        mrs  = m * rs * LOG2E;

        float s3 = 0.f, q3 = 0.f;
#pragma unroll
        for (int u = 0; u < 16; ++u) {
            float4 t = v[u];
            t.x = patch_one(t.x, nrs2, mrs);
            t.y = patch_one(t.y, nrs2, mrs);
            t.z = patch_one(t.z, nrs2, mrs);
            t.w = patch_one(t.w, nrs2, mrs);
            v[u] = t;
            s3 += (t.x + t.y) + (t.z + t.w);
            q3 = fmaf(t.x, t.x, fmaf(t.y, t.y, fmaf(t.z, t.z, fmaf(t.w, t.w, q3))));
        }

        // G: pass 3 (s=256): all 16 waves, separate arrays (no extra barrier)
        wave_reduce2(s3, q3);
        if (lane == 0) { redS2[wave] = s3; redQ2[wave] = q3; }
        __syncthreads();
        {
            float S = 0.f, Q = 0.f;
#pragma unroll
            for (int w = 0; w < 16; ++w) { S += redS2[w]; Q += redQ2[w]; }
            m  = S * (1.0f / 65536.0f);
            rs = rsqrtf(fmaf(-m, m, Q * (1.0f / 65536.0f)) + PEPS);
        }
        nrs2 = rs * -LOG2E;
        mrs  = m * rs * LOG2E;

        // H: apply pass 3 + store
        {
            float* go = out_img + (size_t)(pr * 64) * W + pc * 64;
#pragma unroll
            for (int u = 0; u < 16; ++u) {
                const int r = u * 4 + rlane;
                float4 t = v[u];
                t.x = patch_one(t.x, nrs2, mrs);
                t.y = patch_one(t.y, nrs2, mrs);
                t.z = patch_one(t.z, nrs2, mrs);
                t.w = patch_one(t.w, nrs2, mrs);
                *reinterpret_cast<float4*>(go + (size_t)r * W + c4 * 4) = t;
            }
        }
    }
}

extern "C" void kernel_launch(void* const* d_in, const int* in_sizes, int n_in,
                              void* d_out, int out_size, void* d_ws, size_t ws_size,
                              hipStream_t stream)
{
    const float* x = (const float*)d_in[0];
    float* out = (float*)d_out;
    // 1024 images, 256 persistent blocks x 4 images each; no workspace needed.
    fused_pyramid_pipe<<<256, 1024, 0, stream>>>(x, out);
}